// Round 8
// baseline (3049.314 us; speedup 1.0000x reference)
//
#include <hip/hip_runtime.h>

#define BB 32
#define TT 1000
#define HH 512
#define G4 2048
#define BTH ((size_t)BB * TT * HH)  // elements per output tensor

typedef short short8 __attribute__((ext_vector_type(8)));
typedef float f32x4 __attribute__((ext_vector_type(4)));

__device__ __forceinline__ unsigned short f2bf(float f) {
    union { float f; unsigned u; } v; v.f = f;
    unsigned r = v.u + 0x7FFF + ((v.u >> 16) & 1);  // RNE; inputs finite
    return (unsigned short)(r >> 16);
}

// ring: u32 words [2 slots][8 groups][32 producers x 64 words]
// word = (bf16(h) << 16) | t  -- self-tagged (R2-proven protocol)
// Discovery scratch carved INSIDE the ring (slot1/qb0/cg0 words 0..8):
//   cnt[8] at ring[16384..16391], gate at ring[16392].
//   Clobbered only by (qb0,cg0)'s t=1 publish -- provably after the gate.
#define RING_WORDS (2 * 8 * 32 * 64)   // 32768 u32 = 128KB (proven within ws_size)
#define CNT_BASE 16384
#define GATE_IDX 16392

__global__ void lstm_init_ring(unsigned* ring) {
    int i = blockIdx.x * 256 + threadIdx.x;
    unsigned v = (i >= CNT_BASE && i <= GATE_IDX) ? 0u : 0xFFFFFFFFu;
    __hip_atomic_store(ring + i, v, __ATOMIC_RELAXED, __HIP_MEMORY_SCOPE_AGENT);
}

// LDS-ordering-only barrier (R4-validated): VMEM stays in flight.
#define LDS_BAR() do {                                      \
    asm volatile("s_waitcnt lgkmcnt(0)" ::: "memory");      \
    __builtin_amdgcn_s_barrier();                           \
    asm volatile("" ::: "memory");                          \
    __builtin_amdgcn_sched_barrier(0);                      \
} while (0)

__global__ void __launch_bounds__(256, 1)
lstm_main(const float* __restrict__ wx, const float* __restrict__ u,
          const float* __restrict__ ub, const float* __restrict__ ht0,
          const float* __restrict__ ct0, float* __restrict__ out,
          unsigned* __restrict__ ring)
{
    __shared__ __align__(16) unsigned short lds_h[16 * 512];  // 16KB, XOR-swizzled
    __shared__ float lds_gates[4 * 64];
    __shared__ unsigned pad_1cu[17408];   // 68KB: force 1 block/CU -> 32 blocks/XCD
    __shared__ int s_asn, s_ok;

    const int tid  = threadIdx.x;
    const int bid  = blockIdx.x;
    const int lane = tid & 63;
    const int wv   = tid >> 6;

    if (tid == 0) pad_1cu[0] = 0u;   // keep pad allocated

    // ---- XCD discovery: (qb,cg) = (physical XCD, atomic slot) ----
    if (tid == 0) {
        unsigned xcc = __builtin_amdgcn_s_getreg(0xF814) & 7u;  // HW_REG_XCC_ID (m09)
        unsigned slot = __hip_atomic_fetch_add(ring + CNT_BASE + xcc, 1u,
                                               __ATOMIC_RELAXED, __HIP_MEMORY_SCOPE_AGENT);
        __hip_atomic_fetch_add(ring + GATE_IDX, 1u,
                               __ATOMIC_RELAXED, __HIP_MEMORY_SCOPE_AGENT);
        unsigned g; long spin = 0;
        do {
            g = __hip_atomic_load(ring + GATE_IDX, __ATOMIC_RELAXED,
                                  __HIP_MEMORY_SCOPE_AGENT);
        } while (g < 256u && ++spin < 200000000L);
        int ok = (g == 256u) && (slot < 32u);
        if (ok) {
            for (int x = 0; x < 8; ++x)
                ok &= (__hip_atomic_load(ring + CNT_BASE + x, __ATOMIC_RELAXED,
                                         __HIP_MEMORY_SCOPE_AGENT) == 32u);
        }
        s_ok  = ok;                      // uniform across blocks (stable counters)
        s_asn = (int)((xcc << 5) | (slot & 31u));
    }
    __syncthreads();
    const int qb = s_ok ? (s_asn >> 5) : (bid >> 5);  // batches [qb*4, qb*4+4)
    const int cg = s_ok ? (s_asn & 31) : (bid & 31);  // h/gate cols [cg*16,+16)

    // ---- zero pad rows 4..15 of lds_h ----
    for (int j = 0; j < 3; ++j) {
        int idx8 = tid + j * 256;
        int r = 4 + (idx8 >> 6);
        int k = (idx8 & 63) * 8;
        short8 z = {0, 0, 0, 0, 0, 0, 0, 0};
        *(short8*)&lds_h[(r * 512 + k) ^ ((r & 7) << 3)] = z;
    }
    // ---- stage initial h (f32 -> bf16) ----
    {
        int r = wv, k = lane * 8;
        const float* src = ht0 + (size_t)(qb * 4 + r) * HH + k;
        float4 v0 = *(const float4*)src;
        float4 v1 = *(const float4*)(src + 4);
        union { short8 v8; unsigned short s[8]; } p;
        p.s[0] = f2bf(v0.x); p.s[1] = f2bf(v0.y); p.s[2] = f2bf(v0.z); p.s[3] = f2bf(v0.w);
        p.s[4] = f2bf(v1.x); p.s[5] = f2bf(v1.y); p.s[6] = f2bf(v1.z); p.s[7] = f2bf(v1.w);
        *(short8*)&lds_h[(r * 512 + k) ^ ((r & 7) << 3)] = p.v8;
    }

    // ---- preload u fragments into registers (loop-invariant) ----
    const int arow = lane & 15, ahi = lane >> 4;
    short8 breg[16];
    {
        const float* bp = u + (size_t)(wv * HH + cg * 16 + arow) * HH + ahi * 8;
#pragma unroll
        for (int kk = 0; kk < 16; ++kk) {
            float4 v0 = *(const float4*)(bp + kk * 32);
            float4 v1 = *(const float4*)(bp + kk * 32 + 4);
            union { short8 v8; unsigned short s[8]; } p;
            p.s[0] = f2bf(v0.x); p.s[1] = f2bf(v0.y); p.s[2] = f2bf(v0.z); p.s[3] = f2bf(v0.w);
            p.s[4] = f2bf(v1.x); p.s[5] = f2bf(v1.y); p.s[6] = f2bf(v1.z); p.s[7] = f2bf(v1.w);
            breg[kk] = p.v8;
        }
    }

    const int gate = lane >> 4;
    const int jc   = lane & 15;
    const float bias_r = ub[gate * HH + cg * 16 + jc];

    float c_reg = 0.f;
    if (lane < 16)
        c_reg = ct0[(size_t)(qb * 4 + wv) * HH + cg * 16 + lane];

    const size_t wx0 = (size_t)(qb * 4 + wv) * TT * G4 + gate * HH + cg * 16 + jc;
    float wx_cur = wx[wx0];
    float wx_nxt = wx[wx0 + G4];

    const size_t ob_gate = (size_t)(2 + gate) * BTH +
                           (size_t)(qb * 4 + wv) * TT * HH + cg * 16 + jc;
    const size_t ob_h = (size_t)(qb * 4 + wv) * TT * HH + cg * 16 + lane;

    const int a_off = arow * 512 + ahi * 8;
    const int a_msk = (arow & 7) << 3;

    const int myp = tid >> 3;            // producer 0..31
    const int mw  = (tid & 7) * 8;       // word offset 0..56
    const int mb  = mw >> 4;
    const int mj  = mw & 15;

    int use_local = 1, lhits = 0;        // adaptive local-L2 fast path

    __syncthreads();

    for (int t = 0; t < TT; ++t) {
        // ---- phase 1: acquire h_{t-1} ----
        if (t > 0 && myp != cg) {
            const unsigned base = ((unsigned)((t - 1) & 1) * 8 + (unsigned)qb) * 2048
                                  + myp * 64 + mw;
            const unsigned long long* gsrc = (const unsigned long long*)(ring + base);
            const unsigned tg = (unsigned)(t - 1);
            const unsigned long long want =
                (unsigned long long)tg | ((unsigned long long)tg << 32);
            const unsigned long long msk = 0x0000FFFF0000FFFFull;
            unsigned long long q0, q1, q2, q3;
            bool got = false;
            if (use_local) {
                // local fast path: sc0 loads hit the XCD-shared L2 line that the
                // same-XCD producer's sc0 store updated (~150cy). vmcnt(0) inside
                // the asm: nothing in flight at exit (R5 lesson).
                for (int tr = 0; tr < 6 && !got; ++tr) {
                    asm volatile(
                        "global_load_dwordx2 %0, %4, off sc0\n\t"
                        "global_load_dwordx2 %1, %4, off offset:8 sc0\n\t"
                        "global_load_dwordx2 %2, %4, off offset:16 sc0\n\t"
                        "global_load_dwordx2 %3, %4, off offset:24 sc0\n\t"
                        "s_waitcnt vmcnt(0)"
                        : "=&v"(q0), "=&v"(q1), "=&v"(q2), "=&v"(q3)
                        : "v"(gsrc) : "memory");
                    got = ((q0 & msk) == want) & ((q1 & msk) == want) &
                          ((q2 & msk) == want) & ((q3 & msk) == want);
                }
                if (got) ++lhits;
            }
            if (!got) {
                // R2-proven AGENT path: always correct, guarantees progress
                for (;;) {
                    q0 = __hip_atomic_load(gsrc + 0, __ATOMIC_RELAXED, __HIP_MEMORY_SCOPE_AGENT);
                    q1 = __hip_atomic_load(gsrc + 1, __ATOMIC_RELAXED, __HIP_MEMORY_SCOPE_AGENT);
                    q2 = __hip_atomic_load(gsrc + 2, __ATOMIC_RELAXED, __HIP_MEMORY_SCOPE_AGENT);
                    q3 = __hip_atomic_load(gsrc + 3, __ATOMIC_RELAXED, __HIP_MEMORY_SCOPE_AGENT);
                    if (((q0 & msk) == want) & ((q1 & msk) == want) &
                        ((q2 & msk) == want) & ((q3 & msk) == want)) break;
                }
            }
            union { short8 v8; unsigned u[4]; } pv;
            pv.u[0] = ((unsigned)(q0 >> 16) & 0xFFFFu) | ((unsigned)(q0 >> 48) << 16);
            pv.u[1] = ((unsigned)(q1 >> 16) & 0xFFFFu) | ((unsigned)(q1 >> 48) << 16);
            pv.u[2] = ((unsigned)(q2 >> 16) & 0xFFFFu) | ((unsigned)(q2 >> 48) << 16);
            pv.u[3] = ((unsigned)(q3 >> 16) & 0xFFFFu) | ((unsigned)(q3 >> 48) << 16);
            *(short8*)&lds_h[(mb * 512 + myp * 16 + mj) ^ ((mb & 7) << 3)] = pv.v8;
        }
        if (t == 12 && lhits == 0) use_local = 0;   // local path dead -> pure R2
        __syncthreads();   // S1

        const float wx_use = wx_cur;
        wx_cur = wx_nxt;
        if (t + 2 < TT) wx_nxt = wx[wx0 + (size_t)(t + 2) * G4];   // R2 position

        // ---- phase 2: MFMA (R2-exact) ----
        f32x4 acc0 = {0.f, 0.f, 0.f, 0.f}, acc1 = {0.f, 0.f, 0.f, 0.f};
#pragma unroll
        for (int kk = 0; kk < 8; ++kk) {
            short8 va0 = *(const short8*)&lds_h[(a_off + kk * 32) ^ a_msk];
            short8 va1 = *(const short8*)&lds_h[(a_off + (kk + 8) * 32) ^ a_msk];
            acc0 = __builtin_amdgcn_mfma_f32_16x16x32_bf16(va0, breg[kk], acc0, 0, 0, 0);
            acc1 = __builtin_amdgcn_mfma_f32_16x16x32_bf16(va1, breg[kk + 8], acc1, 0, 0, 0);
        }
        f32x4 g = acc0 + acc1;
        if (lane < 16) {
#pragma unroll
            for (int rr = 0; rr < 4; ++rr)
                lds_gates[rr * 64 + wv * 16 + lane] = g[rr];
        }
        LDS_BAR();   // S2: LDS-only -> wx prefetch stays in flight

        // ---- phase 3: activations, c/h update, dual publish (R2-exact + sc0) ----
        float gv = lds_gates[wv * 64 + lane] + wx_use + bias_r;
        float xs = (gate == 2) ? 2.f * gv : gv;
        float s  = 1.f / (1.f + __expf(-xs));
        float act = (gate == 2) ? 2.f * s - 1.f : s;  // tanh = 2*sigmoid(2x)-1

        float af = __shfl(act, (lane & 15) + 16, 64);
        float ag = __shfl(act, (lane & 15) + 32, 64);
        float ao = __shfl(act, (lane & 15) + 48, 64);
        if (lane < 16) {
            c_reg = af * c_reg + act * ag;
            float e2 = __expf(-2.f * c_reg);
            float th = 2.f / (1.f + e2) - 1.f;
            float hn = ao * th;
            unsigned short hb = f2bf(hn);
            unsigned pk = ((unsigned)hb << 16) | (unsigned)t;
            unsigned* rdst = ring + ((size_t)(t & 1) * 8 + qb) * 2048 +
                             cg * 64 + wv * 16 + lane;
            // sc0 store updates the XCD-shared L2 line (local consumers hit fresh);
            // AGENT store (R2-proven) makes it MALL-visible for the fallback path.
            asm volatile("global_store_dword %0, %1, off sc0"
                         :: "v"(rdst), "v"(pk) : "memory");
            __hip_atomic_store(rdst, pk, __ATOMIC_RELAXED, __HIP_MEMORY_SCOPE_AGENT);
            lds_h[(wv * 512 + cg * 16 + lane) ^ ((wv & 7) << 3)] = hb;
            out[ob_h + (size_t)t * HH] = hn;
            out[BTH + ob_h + (size_t)t * HH] = c_reg;
        }
        out[ob_gate + (size_t)t * HH] = act;
    }
}

extern "C" void kernel_launch(void* const* d_in, const int* in_sizes, int n_in,
                              void* d_out, int out_size, void* d_ws, size_t ws_size,
                              hipStream_t stream) {
    const float* wx = (const float*)d_in[0];
    const float* u  = (const float*)d_in[1];
    const float* ub = (const float*)d_in[2];
    const float* ht = (const float*)d_in[3];
    const float* ct = (const float*)d_in[4];
    float* out = (float*)d_out;
    unsigned* ring = (unsigned*)d_ws;   // 128KB, proven within ws_size

    lstm_init_ring<<<RING_WORDS / 256, 256, 0, stream>>>(ring);

    void* args[] = {(void*)&wx, (void*)&u, (void*)&ub, (void*)&ht,
                    (void*)&ct, (void*)&out, (void*)&ring};
    hipLaunchCooperativeKernel((void*)lstm_main, dim3(256), dim3(256), args, 0, stream);
}

// Round 9
// 1696.719 us; speedup vs baseline: 1.7972x; 1.7972x over previous
//
#include <hip/hip_runtime.h>

#define BB 32
#define TT 1000
#define HH 512
#define G4 2048
#define BTH ((size_t)BB * TT * HH)  // elements per output tensor

typedef short short8 __attribute__((ext_vector_type(8)));
typedef float f32x4 __attribute__((ext_vector_type(4)));

__device__ __forceinline__ unsigned short f2bf(float f) {
    union { float f; unsigned u; } v; v.f = f;
    unsigned r = v.u + 0x7FFF + ((v.u >> 16) & 1);  // RNE; inputs finite
    return (unsigned short)(r >> 16);
}

// ring: u32 words [2 slots][8 groups][32 producers x 64 words]
// word = (bf16(h) << 16) | t  -- self-tagged, fence-free (R2-proven protocol)
#define RING_WORDS (2 * 8 * 32 * 64)   // 32768 u32 = 128KB (proven within ws_size)

__global__ void lstm_init_ring(unsigned* ring) {
    int i = blockIdx.x * 256 + threadIdx.x;
    __hip_atomic_store(ring + i, 0xFFFFFFFFu, __ATOMIC_RELAXED,
                       __HIP_MEMORY_SCOPE_AGENT);
}

// LDS-ordering-only barrier (m194-m199 pattern): VMEM stays in flight.
// Sufficient here: barriers only order LDS producer->consumer; the ring
// protocol is self-tagged retry (needs no ordering at barriers).
#define LDS_BAR() do {                                      \
    asm volatile("s_waitcnt lgkmcnt(0)" ::: "memory");      \
    __builtin_amdgcn_s_barrier();                           \
    asm volatile("" ::: "memory");                          \
    __builtin_amdgcn_sched_barrier(0);                      \
} while (0)

__global__ void __launch_bounds__(256, 1)
lstm_main(const float* __restrict__ wx, const float* __restrict__ u,
          const float* __restrict__ ub, const float* __restrict__ ht0,
          const float* __restrict__ ct0, float* __restrict__ out,
          unsigned* __restrict__ ring)
{
    __shared__ __align__(16) unsigned short lds_h[16 * 512];  // 16KB, XOR-swizzled
    __shared__ float lds_gates[4 * 64];

    const int tid  = threadIdx.x;
    const int bid  = blockIdx.x;
    const int cg   = bid & 31;   // owns h/gate cols [cg*16, cg*16+16)
    const int qb   = bid >> 5;   // owns batches [qb*4, qb*4+4)
    const int lane = tid & 63;
    const int wv   = tid >> 6;

    // ---- zero pad rows 4..15 of lds_h ----
    for (int j = 0; j < 3; ++j) {
        int idx8 = tid + j * 256;
        int r = 4 + (idx8 >> 6);
        int k = (idx8 & 63) * 8;
        short8 z = {0, 0, 0, 0, 0, 0, 0, 0};
        *(short8*)&lds_h[(r * 512 + k) ^ ((r & 7) << 3)] = z;
    }
    // ---- stage initial h (f32 -> bf16) ----
    {
        int r = wv, k = lane * 8;
        const float* src = ht0 + (size_t)(qb * 4 + r) * HH + k;
        float4 v0 = *(const float4*)src;
        float4 v1 = *(const float4*)(src + 4);
        union { short8 v8; unsigned short s[8]; } p;
        p.s[0] = f2bf(v0.x); p.s[1] = f2bf(v0.y); p.s[2] = f2bf(v0.z); p.s[3] = f2bf(v0.w);
        p.s[4] = f2bf(v1.x); p.s[5] = f2bf(v1.y); p.s[6] = f2bf(v1.z); p.s[7] = f2bf(v1.w);
        *(short8*)&lds_h[(r * 512 + k) ^ ((r & 7) << 3)] = p.v8;
    }

    // ---- preload u fragments into registers (loop-invariant) ----
    const int arow = lane & 15, ahi = lane >> 4;
    short8 breg[16];
    {
        const float* bp = u + (size_t)(wv * HH + cg * 16 + arow) * HH + ahi * 8;
#pragma unroll
        for (int kk = 0; kk < 16; ++kk) {
            float4 v0 = *(const float4*)(bp + kk * 32);
            float4 v1 = *(const float4*)(bp + kk * 32 + 4);
            union { short8 v8; unsigned short s[8]; } p;
            p.s[0] = f2bf(v0.x); p.s[1] = f2bf(v0.y); p.s[2] = f2bf(v0.z); p.s[3] = f2bf(v0.w);
            p.s[4] = f2bf(v1.x); p.s[5] = f2bf(v1.y); p.s[6] = f2bf(v1.z); p.s[7] = f2bf(v1.w);
            breg[kk] = p.v8;
        }
    }

    const int gate = lane >> 4;
    const int jc   = lane & 15;
    const float bias_r = ub[gate * HH + cg * 16 + jc];

    float c_reg = 0.f;
    if (lane < 16)
        c_reg = ct0[(size_t)(qb * 4 + wv) * HH + cg * 16 + lane];

    const size_t wx0 = (size_t)(qb * 4 + wv) * TT * G4 + gate * HH + cg * 16 + jc;
    float wx_cur = wx[wx0];
    float wx_nxt = wx[wx0 + G4];

    const size_t ob_gate = (size_t)(2 + gate) * BTH +
                           (size_t)(qb * 4 + wv) * TT * HH + cg * 16 + jc;
    const size_t ob_h = (size_t)(qb * 4 + wv) * TT * HH + cg * 16 + lane;

    const int a_off = arow * 512 + ahi * 8;
    const int a_msk = (arow & 7) << 3;

    const int myp = tid >> 3;            // producer 0..31
    const int mw  = (tid & 7) * 8;       // word offset 0..56
    const int mb  = mw >> 4;
    const int mj  = mw & 15;

    __syncthreads();   // setup complete (one full drain, harmless)

    for (int t = 0; t < TT; ++t) {
        // ---- phase 1: acquire h_{t-1} (R2-proven AGENT poll) ----
        if (t > 0 && myp != cg) {
            const unsigned long long* src = (const unsigned long long*)
                (ring + ((size_t)((t - 1) & 1) * 8 + qb) * 2048 + myp * 64 + mw);
            const unsigned tg = (unsigned)(t - 1);
            const unsigned long long want =
                (unsigned long long)tg | ((unsigned long long)tg << 32);
            const unsigned long long msk = 0x0000FFFF0000FFFFull;
            unsigned long long q0, q1, q2, q3;
            for (;;) {
                q0 = __hip_atomic_load(src + 0, __ATOMIC_RELAXED, __HIP_MEMORY_SCOPE_AGENT);
                q1 = __hip_atomic_load(src + 1, __ATOMIC_RELAXED, __HIP_MEMORY_SCOPE_AGENT);
                q2 = __hip_atomic_load(src + 2, __ATOMIC_RELAXED, __HIP_MEMORY_SCOPE_AGENT);
                q3 = __hip_atomic_load(src + 3, __ATOMIC_RELAXED, __HIP_MEMORY_SCOPE_AGENT);
                if (((q0 & msk) == want) & ((q1 & msk) == want) &
                    ((q2 & msk) == want) & ((q3 & msk) == want)) break;
            }
            union { short8 v8; unsigned u[4]; } pv;
            pv.u[0] = ((unsigned)(q0 >> 16) & 0xFFFFu) | ((unsigned)(q0 >> 48) << 16);
            pv.u[1] = ((unsigned)(q1 >> 16) & 0xFFFFu) | ((unsigned)(q1 >> 48) << 16);
            pv.u[2] = ((unsigned)(q2 >> 16) & 0xFFFFu) | ((unsigned)(q2 >> 48) << 16);
            pv.u[3] = ((unsigned)(q3 >> 16) & 0xFFFFu) | ((unsigned)(q3 >> 48) << 16);
            *(short8*)&lds_h[(mb * 512 + myp * 16 + mj) ^ ((mb & 7) << 3)] = pv.v8;
        }
        LDS_BAR();   // S1: LDS ordering only (output-store acks stay in flight)

        const float wx_use = wx_cur;
        wx_cur = wx_nxt;
        if (t + 2 < TT) wx_nxt = wx[wx0 + (size_t)(t + 2) * G4];   // R2 position

        // ---- phase 2: MFMA (R2-exact) ----
        f32x4 acc0 = {0.f, 0.f, 0.f, 0.f}, acc1 = {0.f, 0.f, 0.f, 0.f};
#pragma unroll
        for (int kk = 0; kk < 8; ++kk) {
            short8 va0 = *(const short8*)&lds_h[(a_off + kk * 32) ^ a_msk];
            short8 va1 = *(const short8*)&lds_h[(a_off + (kk + 8) * 32) ^ a_msk];
            acc0 = __builtin_amdgcn_mfma_f32_16x16x32_bf16(va0, breg[kk], acc0, 0, 0, 0);
            acc1 = __builtin_amdgcn_mfma_f32_16x16x32_bf16(va1, breg[kk + 8], acc1, 0, 0, 0);
        }
        f32x4 g = acc0 + acc1;
        if (lane < 16) {
#pragma unroll
            for (int rr = 0; rr < 4; ++rr)
                lds_gates[rr * 64 + wv * 16 + lane] = g[rr];
        }
        LDS_BAR();   // S2: LDS ordering only -> wx prefetch NOT drained here

        // ---- phase 3: activations, c/h update, publish (R2-exact) ----
        float gv = lds_gates[wv * 64 + lane] + wx_use + bias_r;
        float xs = (gate == 2) ? 2.f * gv : gv;
        float s  = 1.f / (1.f + __expf(-xs));
        float act = (gate == 2) ? 2.f * s - 1.f : s;  // tanh = 2*sigmoid(2x)-1

        float af = __shfl(act, (lane & 15) + 16, 64);
        float ag = __shfl(act, (lane & 15) + 32, 64);
        float ao = __shfl(act, (lane & 15) + 48, 64);
        if (lane < 16) {
            c_reg = af * c_reg + act * ag;
            float e2 = __expf(-2.f * c_reg);
            float th = 2.f / (1.f + e2) - 1.f;
            float hn = ao * th;
            unsigned short hb = f2bf(hn);
            // publish FIRST (critical inter-block path)
            unsigned pk = ((unsigned)hb << 16) | (unsigned)t;
            __hip_atomic_store(ring + ((size_t)(t & 1) * 8 + qb) * 2048 +
                                   cg * 64 + wv * 16 + lane,
                               pk, __ATOMIC_RELAXED, __HIP_MEMORY_SCOPE_AGENT);
            lds_h[(wv * 512 + cg * 16 + lane) ^ ((wv & 7) << 3)] = hb;
            out[ob_h + (size_t)t * HH] = hn;
            out[BTH + ob_h + (size_t)t * HH] = c_reg;
        }
        out[ob_gate + (size_t)t * HH] = act;
    }
}

extern "C" void kernel_launch(void* const* d_in, const int* in_sizes, int n_in,
                              void* d_out, int out_size, void* d_ws, size_t ws_size,
                              hipStream_t stream) {
    const float* wx = (const float*)d_in[0];
    const float* u  = (const float*)d_in[1];
    const float* ub = (const float*)d_in[2];
    const float* ht = (const float*)d_in[3];
    const float* ct = (const float*)d_in[4];
    float* out = (float*)d_out;
    unsigned* ring = (unsigned*)d_ws;   // 128KB, proven within ws_size

    lstm_init_ring<<<RING_WORDS / 256, 256, 0, stream>>>(ring);

    void* args[] = {(void*)&wx, (void*)&u, (void*)&ub, (void*)&ht,
                    (void*)&ct, (void*)&out, (void*)&ring};
    hipLaunchCooperativeKernel((void*)lstm_main, dim3(256), dim3(256), args, 0, stream);
}